// Round 10
// baseline (289.520 us; speedup 1.0000x reference)
//
#include <hip/hip_runtime.h>
#include <stdint.h>
#include <stddef.h>

#define KH   512
#define DF   3072
#define EPSF 1e-5f
#define PPB  8            // positions per block
#define ROWS 48           // PPB*6
#define TSS  516          // Ts row stride (floats), padded

typedef __attribute__((ext_vector_type(4))) float f32x4;
typedef __attribute__((ext_vector_type(2))) float f32x2;
typedef __attribute__((ext_vector_type(8))) short bf16x8;
typedef __attribute__((ext_vector_type(4))) unsigned int u32x4;

__device__ __forceinline__ unsigned short f2bf(float f) {
  union { float f; unsigned u; } c; c.f = f;
  unsigned u = c.u;
  u += 0x7fffu + ((u >> 16) & 1u);     // RNE
  return (unsigned short)(u >> 16);
}
__device__ __forceinline__ unsigned short f2bf_trunc(float f) {
  union { float f; unsigned u; } c; c.f = f;
  return (unsigned short)(c.u >> 16);  // truncation: 1 op
}
__device__ __forceinline__ float bf2f(unsigned short u) {
  union { unsigned u; float f; } c; c.u = ((unsigned)u) << 16;
  return c.f;
}
__device__ __forceinline__ float bfl(unsigned u) {   // low bf16 of u32 -> f32
  union { unsigned u; float f; } c; c.u = u << 16;
  return c.f;
}
__device__ __forceinline__ float bfh(unsigned u) {   // high bf16 of u32 -> f32
  union { unsigned u; float f; } c; c.u = u & 0xffff0000u;
  return c.f;
}

// Weight images (verified R5 layout): region A (0): alpha*gamma,
// region B (+512KB): beta_w*gamma.
// byte(f,s) = (((f>>2)*16 + s)*4 + (f&3))*1024 + (h*16+co)*16 + e*2,  f = o>>4.
// Per-wave per-step fragment read = coalesced 1KB dwordx4 per fragment.
__global__ __launch_bounds__(256) void prep_w(const float* __restrict__ cw,
                                              const float* __restrict__ cb,
                                              const float* __restrict__ nw,
                                              const float* __restrict__ nb,
                                              unsigned char* __restrict__ wbt,
                                              float* __restrict__ c12) {
  const int o = blockIdx.x;
  const int t = threadIdx.x;
  const int wn = o >> 6, nn = (o >> 4) & 3, co = o & 15;
  float c1 = 0.f, c2 = 0.f;
  for (int k = t; k < KH; k += 256) {
    float w0 = cw[o * 1024 + 2 * k];
    float w1 = cw[o * 1024 + 2 * k + 1];
    float a  = w0 - w1;
    float g  = nw[k], b = nb[k];
    int s = k >> 5, kin = k & 31, h = kin >> 3, e = kin & 7;
    size_t base = (size_t)(((wn * 16 + s) * 4 + nn)) * 1024 + (h * 16 + co) * 16 + e * 2;
    *(unsigned short*)(wbt + base)          = f2bf(a * g);    // alpha*gamma
    *(unsigned short*)(wbt + base + 524288) = f2bf(w1 * g);   // beta_w*gamma
    float tt = a + 6.f * w1;
    c1 += tt * b;
    c2 += tt * g;
  }
  #pragma unroll
  for (int off = 32; off >= 1; off >>= 1) {
    c1 += __shfl_xor(c1, off);
    c2 += __shfl_xor(c2, off);
  }
  __shared__ float s1[4], s2[4];
  int wid = t >> 6, lane = t & 63;
  if (lane == 0) { s1[wid] = c1; s2[wid] = c2; }
  __syncthreads();
  if (t == 0) {
    c12[o]      = s1[0] + s1[1] + s1[2] + s1[3] + cb[o];
    c12[KH + o] = s2[0] + s2[1] + s2[2] + s2[3];
  }
}

// Block: 8 positions (48 rows) x 512 o. 1024 threads = 16 waves; wave wid owns
// o-slice wid*32..+32 for term1, term2 AND epilogue. 2 barriers total.
// 24 VGPR acc + single-buffered B loads -> <=64 regs -> 8 waves/SIMD,
// 2 blocks/CU co-resident = 32 waves/CU (100% nominal occupancy).
__global__ __launch_bounds__(1024, 8) void fused_main(
    const float* __restrict__ x,
    const unsigned char* __restrict__ wbt,
    const float* __restrict__ c12,
    float* __restrict__ out)
{
  __shared__ unsigned char As[ROWS * 1024];   // 48 KB raw-x panel (bf16, swizzled)
  __shared__ unsigned char Sx[PPB * 1024];    // 8 KB raw color-sum panel
  __shared__ float Ts[PPB * TSS];             // 16.1 KB term2 (f32)
  __shared__ float st[PPB * 2];

  const int tid  = threadIdx.x;
  const int lane = tid & 63;
  const int wid  = tid >> 6;     // 0..15 : o-slice owner
  const int co   = lane & 15;
  const int h    = lane >> 4;
  const int rvb  = h << 2;
  const size_t r0 = (size_t)blockIdx.x * PPB;

  float C1r[2], C2r[2];
  #pragma unroll
  for (int n = 0; n < 2; n++) {
    int o = wid * 32 + n * 16 + co;
    C1r[n] = c12[o];
    C2r[n] = c12[KH + o];
  }

  // per-wave fragment base inside each image region: f = wid*2 + n
  // byte(f,s) = ((f>>2)*64 + s*4 + (f&3)) * 1024 + lane*16
  const size_t wAoff = ((size_t)(wid >> 1) * 65536) + ((size_t)(wid & 1) * 2048)
                     + (size_t)lane * 16;
  bf16x8 bv[2];

  // ---- P1: cooperative contiguous x load + P2a scatter-convert (trunc) ----
  {
    const float* xb = x + r0 * DF;
    f32x4 q[6];
    #pragma unroll
    for (int i = 0; i < 6; i++) q[i] = *(const f32x4*)(xb + i * 4096 + tid * 4);

    // prefetch term1 step-0 B fragments (independent of As/Sx; hides L2
    // latency across the two barriers)
    #pragma unroll
    for (int n = 0; n < 2; n++)
      bv[n] = *(const bf16x8*)(wbt + wAoff + n * 1024);

    #pragma unroll
    for (int i = 0; i < 6; i++) {
      int base = i * 4096 + tid * 4;
      int pl   = base / 3072;
      int rem  = base - pl * 3072;
      int k0   = rem / 6;
      int d0   = rem - k0 * 6;
      #pragma unroll
      for (int e = 0; e < 4; e++) {
        int d = d0 + e, k = k0;
        if (d >= 6) { d -= 6; k += 1; }
        int row  = pl * 6 + d;
        int byte = row * 1024 + ((((k >> 3) ^ (row & 7)) << 4)) + (k & 7) * 2;
        *(unsigned short*)(As + byte) = f2bf_trunc(q[i][e]);
      }
    }
  }
  __syncthreads();                          // B1: As ready

  // ---- P2b: waves 0-7 own position wid: LN stats + color-sum panel ----
  if (wid < 8) {
    float vals[48];
    #pragma unroll
    for (int d = 0; d < 6; d++) {
      int row = wid * 6 + d;
      u32x4 v = *(const u32x4*)(As + row * 1024 + ((lane ^ (row & 7)) << 4));
      #pragma unroll
      for (int jj = 0; jj < 4; jj++) {
        vals[d * 8 + 2 * jj]     = bfl(v[jj]);
        vals[d * 8 + 2 * jj + 1] = bfh(v[jj]);
      }
    }
    float s = 0.f, sq = 0.f;
    #pragma unroll
    for (int i = 0; i < 48; i++) { s += vals[i]; sq += vals[i] * vals[i]; }
    #pragma unroll
    for (int off = 32; off >= 1; off >>= 1) {
      s  += __shfl_xor(s,  off);
      sq += __shfl_xor(sq, off);
    }
    float mean = s * (1.f / 3072.f);
    float var  = sq * (1.f / 3072.f) - mean * mean;
    float rstd = rsqrtf(var + EPSF);
    if (lane == 0) { st[2 * wid] = mean; st[2 * wid + 1] = rstd; }
    bf16x8 sv;
    #pragma unroll
    for (int g = 0; g < 8; g++) {
      float ss = vals[g] + vals[8 + g] + vals[16 + g] + vals[24 + g] +
                 vals[32 + g] + vals[40 + g];
      sv[g] = (short)f2bf(ss);
    }
    *(bf16x8*)(Sx + wid * 1024 + ((lane ^ (wid & 7)) << 4)) = sv;
  }
  __syncthreads();                          // B2: Sx + st ready (LAST barrier)

  // ---- term1: 48x32 slice over K=512; single-buffered B (TLP hides L2) ----
  f32x4 acc1[3][2];
  #pragma unroll
  for (int m = 0; m < 3; m++)
    #pragma unroll
    for (int n = 0; n < 2; n++) acc1[m][n] = (f32x4){0.f, 0.f, 0.f, 0.f};

  int arow[3], ar7[3];
  #pragma unroll
  for (int m = 0; m < 3; m++) {
    int row = m * 16 + co;
    arow[m] = row * 1024;  ar7[m] = row & 7;
  }

  #pragma unroll 1
  for (int s = 0; s < 16; s++) {
    int g6 = s * 4 + h;
    bf16x8 af[3];
    #pragma unroll
    for (int m = 0; m < 3; m++)
      af[m] = *(const bf16x8*)(As + arow[m] + ((g6 ^ ar7[m]) << 4));
    #pragma unroll
    for (int m = 0; m < 3; m++)
      #pragma unroll
      for (int n = 0; n < 2; n++)
        acc1[m][n] = __builtin_amdgcn_mfma_f32_16x16x32_bf16(af[m], bv[n], acc1[m][n], 0, 0, 0);
    if (s + 1 < 16) {
      #pragma unroll
      for (int n = 0; n < 2; n++)
        bv[n] = *(const bf16x8*)(wbt + wAoff + (size_t)(s + 1) * 4096 + n * 1024);
    }
  }

  // ---- term2: 8x32 slice over K=512; same-wave o-slice; result -> Ts ----
  {
    f32x4 acc2[2];
    acc2[0] = (f32x4){0.f, 0.f, 0.f, 0.f};
    acc2[1] = (f32x4){0.f, 0.f, 0.f, 0.f};
    const int sxr = (co & 7);
    bf16x8 cA[2];
    #pragma unroll
    for (int n = 0; n < 2; n++)
      cA[n] = *(const bf16x8*)(wbt + 524288 + wAoff + n * 1024);
    #pragma unroll 1
    for (int s = 0; s < 16; s++) {
      int g6 = s * 4 + h;
      bf16x8 a2 = *(const bf16x8*)(Sx + sxr * 1024 + ((g6 ^ sxr) << 4));
      #pragma unroll
      for (int n = 0; n < 2; n++)
        acc2[n] = __builtin_amdgcn_mfma_f32_16x16x32_bf16(a2, cA[n], acc2[n], 0, 0, 0);
      if (s + 1 < 16) {
        #pragma unroll
        for (int n = 0; n < 2; n++)
          cA[n] = *(const bf16x8*)(wbt + 524288 + wAoff + (size_t)(s + 1) * 4096 + n * 1024);
      }
    }
    // output rows 0..7 = positions; rows 8..15 aliased duplicates - skip.
    if (h < 2) {
      #pragma unroll
      for (int n = 0; n < 2; n++)
        #pragma unroll
        for (int v = 0; v < 4; v++)
          Ts[(rvb + v) * TSS + wid * 32 + n * 16 + co] = acc2[n][v];
    }
  }
  // NO barrier: Ts slice [*, wid*32..+32] is written and read by wave wid only.

  // ---- epilogue: residual from As (LDS), direct wide stores ----
  #pragma unroll
  for (int n = 0; n < 2; n++) {
    const int o = wid * 32 + n * 16 + co;
    const int swzo = o >> 3;
    const int ob2 = (o & 7) * 2;
    #pragma unroll
    for (int m = 0; m < 3; m++) {
      int j0  = m * 16 + rvb;
      int pl0 = j0 / 6;
      int d0  = j0 - pl0 * 6;
      float mean0 = st[2 * pl0], rstd0 = st[2 * pl0 + 1];
      float t20   = Ts[pl0 * TSS + o];
      float cc0   = C1r[n] - mean0 * rstd0 * C2r[n];
      if (d0 < 3) {
        f32x4 ov;
        #pragma unroll
        for (int v = 0; v < 4; v++) {
          int j = j0 + v;
          unsigned short rx = *(const unsigned short*)(
              As + j * 1024 + ((swzo ^ (j & 7)) << 4) + ob2);
          ov[v] = bf2f(rx) + fmaxf(rstd0 * (acc1[m][n][v] + t20) + cc0, 0.f);
        }
        *(f32x4*)(out + (r0 + pl0) * DF + o * 6 + d0) = ov;
      } else {                               // d0 == 4: split 2 + 2
        int pl1 = pl0 + 1;
        float mean1 = st[2 * pl1], rstd1 = st[2 * pl1 + 1];
        float t21   = Ts[pl1 * TSS + o];
        float cc1   = C1r[n] - mean1 * rstd1 * C2r[n];
        f32x2 o0, o1;
        #pragma unroll
        for (int v = 0; v < 2; v++) {
          int j = j0 + v;
          unsigned short rx = *(const unsigned short*)(
              As + j * 1024 + ((swzo ^ (j & 7)) << 4) + ob2);
          o0[v] = bf2f(rx) + fmaxf(rstd0 * (acc1[m][n][v] + t20) + cc0, 0.f);
        }
        #pragma unroll
        for (int v = 2; v < 4; v++) {
          int j = j0 + v;
          unsigned short rx = *(const unsigned short*)(
              As + j * 1024 + ((swzo ^ (j & 7)) << 4) + ob2);
          o1[v - 2] = bf2f(rx) + fmaxf(rstd1 * (acc1[m][n][v] + t21) + cc1, 0.f);
        }
        *(f32x2*)(out + (r0 + pl0) * DF + o * 6 + 4) = o0;
        *(f32x2*)(out + (r0 + pl1) * DF + o * 6)     = o1;
      }
    }
  }
}

extern "C" void kernel_launch(void* const* d_in, const int* in_sizes, int n_in,
                              void* d_out, int out_size, void* d_ws, size_t ws_size,
                              hipStream_t stream) {
  (void)n_in; (void)out_size; (void)ws_size;
  const float* x  = (const float*)d_in[0];
  const float* cw = (const float*)d_in[1];
  const float* cb = (const float*)d_in[2];
  const float* nw = (const float*)d_in[3];
  const float* nb = (const float*)d_in[4];
  float* out = (float*)d_out;

  unsigned char* wbt = (unsigned char*)d_ws;                    // 1 MB images
  float* c12 = (float*)((char*)d_ws + (size_t)1024 * 1024);     // 4 KB

  prep_w<<<512, 256, 0, stream>>>(cw, cb, nw, nb, wbt, c12);

  const int R = in_sizes[0] / DF;            // 24576 positions
  fused_main<<<R / PPB, 1024, 0, stream>>>(x, wbt, c12, out);
}

// Round 11
// 238.356 us; speedup vs baseline: 1.2147x; 1.2147x over previous
//
#include <hip/hip_runtime.h>
#include <stdint.h>
#include <stddef.h>

#define KH   512
#define DF   3072
#define EPSF 1e-5f
#define PPB  8            // positions per block
#define ROWS 48           // PPB*6
#define TSS  516          // Ts row stride (floats), padded

typedef __attribute__((ext_vector_type(4))) float f32x4;
typedef __attribute__((ext_vector_type(2))) float f32x2;
typedef __attribute__((ext_vector_type(8))) short bf16x8;
typedef __attribute__((ext_vector_type(4))) unsigned int u32x4;

__device__ __forceinline__ unsigned short f2bf(float f) {
  union { float f; unsigned u; } c; c.f = f;
  unsigned u = c.u;
  u += 0x7fffu + ((u >> 16) & 1u);     // RNE
  return (unsigned short)(u >> 16);
}
__device__ __forceinline__ unsigned short f2bf_trunc(float f) {
  union { float f; unsigned u; } c; c.f = f;
  return (unsigned short)(c.u >> 16);  // truncation: 1 op
}
__device__ __forceinline__ float bf2f(unsigned short u) {
  union { unsigned u; float f; } c; c.u = ((unsigned)u) << 16;
  return c.f;
}
__device__ __forceinline__ float bfl(unsigned u) {   // low bf16 of u32 -> f32
  union { unsigned u; float f; } c; c.u = u << 16;
  return c.f;
}
__device__ __forceinline__ float bfh(unsigned u) {   // high bf16 of u32 -> f32
  union { unsigned u; float f; } c; c.u = u & 0xffff0000u;
  return c.f;
}

// Weight images (verified R5 layout): region A (0): alpha*gamma,
// region B (+512KB): beta_w*gamma.
// byte(f,s) = (((f>>2)*16 + s)*4 + (f&3))*1024 + (h*16+co)*16 + e*2,  f = o>>4.
// Per-wave per-step fragment read = contiguous 4KB = 4 coalesced 1KB dwordx4.
__global__ __launch_bounds__(256) void prep_w(const float* __restrict__ cw,
                                              const float* __restrict__ cb,
                                              const float* __restrict__ nw,
                                              const float* __restrict__ nb,
                                              unsigned char* __restrict__ wbt,
                                              float* __restrict__ c12) {
  const int o = blockIdx.x;
  const int t = threadIdx.x;
  const int wn = o >> 6, nn = (o >> 4) & 3, co = o & 15;
  float c1 = 0.f, c2 = 0.f;
  for (int k = t; k < KH; k += 256) {
    float w0 = cw[o * 1024 + 2 * k];
    float w1 = cw[o * 1024 + 2 * k + 1];
    float a  = w0 - w1;
    float g  = nw[k], b = nb[k];
    int s = k >> 5, kin = k & 31, h = kin >> 3, e = kin & 7;
    size_t base = (size_t)(((wn * 16 + s) * 4 + nn)) * 1024 + (h * 16 + co) * 16 + e * 2;
    *(unsigned short*)(wbt + base)          = f2bf(a * g);    // alpha*gamma
    *(unsigned short*)(wbt + base + 524288) = f2bf(w1 * g);   // beta_w*gamma
    float tt = a + 6.f * w1;
    c1 += tt * b;
    c2 += tt * g;
  }
  #pragma unroll
  for (int off = 32; off >= 1; off >>= 1) {
    c1 += __shfl_xor(c1, off);
    c2 += __shfl_xor(c2, off);
  }
  __shared__ float s1[4], s2[4];
  int wid = t >> 6, lane = t & 63;
  if (lane == 0) { s1[wid] = c1; s2[wid] = c2; }
  __syncthreads();
  if (t == 0) {
    c12[o]      = s1[0] + s1[1] + s1[2] + s1[3] + cb[o];
    c12[KH + o] = s2[0] + s2[1] + s2[2] + s2[3];
  }
}

// Block: 8 positions (48 rows) x 512 o. 512 threads = 8 waves; wave wid owns
// o-slice wid*64..+64 for term1, term2 AND epilogue (2 barriers total).
// 3072 blocks, ~72.6 KB LDS -> 2 blocks/CU co-resident; 4 waves/SIMD.
// A-fragments AND B-fragments register double-buffered in the K loops.
__global__ __launch_bounds__(512, 4) void fused_main(
    const float* __restrict__ x,
    const unsigned char* __restrict__ wbt,
    const float* __restrict__ c12,
    float* __restrict__ out)
{
  __shared__ unsigned char As[ROWS * 1024];   // 48 KB raw-x panel (bf16, swizzled)
  __shared__ unsigned char Sx[PPB * 1024];    // 8 KB raw color-sum panel
  __shared__ float Ts[PPB * TSS];             // 16.1 KB term2 (f32)
  __shared__ float st[PPB * 2];

  const int tid  = threadIdx.x;
  const int lane = tid & 63;
  const int wid  = tid >> 6;     // 0..7 : o-slice AND position owner
  const int co   = lane & 15;
  const int h    = lane >> 4;
  const int rvb  = h << 2;
  const size_t r0 = (size_t)blockIdx.x * PPB;

  const unsigned char* wA = wbt + (size_t)wid * 65536;
  bf16x8 bvA[4], bvB[4];

  // ---- P1: cooperative contiguous x load + P2a scatter-convert (trunc) ----
  {
    const float* xb = x + r0 * DF;
    f32x4 q[12];
    #pragma unroll
    for (int i = 0; i < 12; i++) q[i] = *(const f32x4*)(xb + i * 2048 + tid * 4);

    // prefetch term1's step-0 B fragments (independent of As/Sx; hides L2
    // latency across the two barriers)
    #pragma unroll
    for (int n = 0; n < 4; n++)
      bvA[n] = *(const bf16x8*)(wA + n * 1024 + lane * 16);

    #pragma unroll
    for (int i = 0; i < 12; i++) {
      int base = i * 2048 + tid * 4;
      int pl   = base / 3072;
      int rem  = base - pl * 3072;
      int k0   = rem / 6;
      int d0   = rem - k0 * 6;
      #pragma unroll
      for (int e = 0; e < 4; e++) {
        int d = d0 + e, k = k0;
        if (d >= 6) { d -= 6; k += 1; }
        int row  = pl * 6 + d;
        int byte = row * 1024 + ((((k >> 3) ^ (row & 7)) << 4)) + (k & 7) * 2;
        *(unsigned short*)(As + byte) = f2bf_trunc(q[i][e]);
      }
    }
  }
  __syncthreads();                          // B1: As ready

  // ---- P2b: wave wid owns position wid: LN stats + color-sum panel ----
  {
    float vals[48];
    #pragma unroll
    for (int d = 0; d < 6; d++) {
      int row = wid * 6 + d;
      u32x4 v = *(const u32x4*)(As + row * 1024 + ((lane ^ (row & 7)) << 4));
      #pragma unroll
      for (int jj = 0; jj < 4; jj++) {
        vals[d * 8 + 2 * jj]     = bfl(v[jj]);
        vals[d * 8 + 2 * jj + 1] = bfh(v[jj]);
      }
    }
    float s = 0.f, sq = 0.f;
    #pragma unroll
    for (int i = 0; i < 48; i++) { s += vals[i]; sq += vals[i] * vals[i]; }
    #pragma unroll
    for (int off = 32; off >= 1; off >>= 1) {
      s  += __shfl_xor(s,  off);
      sq += __shfl_xor(sq, off);
    }
    float mean = s * (1.f / 3072.f);
    float var  = sq * (1.f / 3072.f) - mean * mean;
    float rstd = rsqrtf(var + EPSF);
    if (lane == 0) { st[2 * wid] = mean; st[2 * wid + 1] = rstd; }
    bf16x8 sv;
    #pragma unroll
    for (int g = 0; g < 8; g++) {
      float ss = vals[g] + vals[8 + g] + vals[16 + g] + vals[24 + g] +
                 vals[32 + g] + vals[40 + g];
      sv[g] = (short)f2bf(ss);
    }
    *(bf16x8*)(Sx + wid * 1024 + ((lane ^ (wid & 7)) << 4)) = sv;
  }
  __syncthreads();                          // B2: Sx + st ready (LAST barrier)

  // ---- term1: 48x512 over K=512; A and B register double-buffered ----
  f32x4 acc1[3][4];
  #pragma unroll
  for (int m = 0; m < 3; m++)
    #pragma unroll
    for (int n = 0; n < 4; n++) acc1[m][n] = (f32x4){0.f, 0.f, 0.f, 0.f};

  int arow[3], ar7[3];
  #pragma unroll
  for (int m = 0; m < 3; m++) {
    int row = m * 16 + co;
    arow[m] = row * 1024;  ar7[m] = row & 7;
  }

  {
    bf16x8 afA[3], afB[3];
    #pragma unroll
    for (int m = 0; m < 3; m++)               // step-0 A fragments
      afA[m] = *(const bf16x8*)(As + arow[m] + ((h ^ ar7[m]) << 4));

    #pragma unroll 1
    for (int s = 0; s < 16; s += 2) {
      // prefetch step s+1 (A from LDS, B from L2)
      {
        int g6 = (s + 1) * 4 + h;
        #pragma unroll
        for (int m = 0; m < 3; m++)
          afB[m] = *(const bf16x8*)(As + arow[m] + ((g6 ^ ar7[m]) << 4));
        const unsigned char* pn = wA + (size_t)(s + 1) * 4096;
        #pragma unroll
        for (int n = 0; n < 4; n++)
          bvB[n] = *(const bf16x8*)(pn + n * 1024 + lane * 16);
      }
      // MFMA step s
      #pragma unroll
      for (int m = 0; m < 3; m++)
        #pragma unroll
        for (int n = 0; n < 4; n++)
          acc1[m][n] = __builtin_amdgcn_mfma_f32_16x16x32_bf16(afA[m], bvA[n], acc1[m][n], 0, 0, 0);
      // prefetch step s+2
      if (s + 2 < 16) {
        int g6 = (s + 2) * 4 + h;
        #pragma unroll
        for (int m = 0; m < 3; m++)
          afA[m] = *(const bf16x8*)(As + arow[m] + ((g6 ^ ar7[m]) << 4));
        const unsigned char* pn2 = wA + (size_t)(s + 2) * 4096;
        #pragma unroll
        for (int n = 0; n < 4; n++)
          bvA[n] = *(const bf16x8*)(pn2 + n * 1024 + lane * 16);
      }
      // MFMA step s+1
      #pragma unroll
      for (int m = 0; m < 3; m++)
        #pragma unroll
        for (int n = 0; n < 4; n++)
          acc1[m][n] = __builtin_amdgcn_mfma_f32_16x16x32_bf16(afB[m], bvB[n], acc1[m][n], 0, 0, 0);
    }
  }

  // ---- term2: 8x512 over K=512; same-wave o-slice; result -> Ts ----
  {
    f32x4 acc2[4];
    #pragma unroll
    for (int n = 0; n < 4; n++) acc2[n] = (f32x4){0.f, 0.f, 0.f, 0.f};
    const unsigned char* wB2 = wbt + 524288 + (size_t)wid * 65536;
    const int sxr = (co & 7);
    bf16x8 cA[4], cB[4];
    bf16x8 a2A, a2B;
    #pragma unroll
    for (int n = 0; n < 4; n++)
      cA[n] = *(const bf16x8*)(wB2 + n * 1024 + lane * 16);
    a2A = *(const bf16x8*)(Sx + sxr * 1024 + ((h ^ sxr) << 4));

    #pragma unroll 1
    for (int s = 0; s < 16; s += 2) {
      {
        int g6 = (s + 1) * 4 + h;
        a2B = *(const bf16x8*)(Sx + sxr * 1024 + ((g6 ^ sxr) << 4));
        const unsigned char* pn = wB2 + (size_t)(s + 1) * 4096;
        #pragma unroll
        for (int n = 0; n < 4; n++)
          cB[n] = *(const bf16x8*)(pn + n * 1024 + lane * 16);
      }
      #pragma unroll
      for (int n = 0; n < 4; n++)
        acc2[n] = __builtin_amdgcn_mfma_f32_16x16x32_bf16(a2A, cA[n], acc2[n], 0, 0, 0);
      if (s + 2 < 16) {
        int g6 = (s + 2) * 4 + h;
        a2A = *(const bf16x8*)(Sx + sxr * 1024 + ((g6 ^ sxr) << 4));
        const unsigned char* pn2 = wB2 + (size_t)(s + 2) * 4096;
        #pragma unroll
        for (int n = 0; n < 4; n++)
          cA[n] = *(const bf16x8*)(pn2 + n * 1024 + lane * 16);
      }
      #pragma unroll
      for (int n = 0; n < 4; n++)
        acc2[n] = __builtin_amdgcn_mfma_f32_16x16x32_bf16(a2B, cB[n], acc2[n], 0, 0, 0);
    }
    // rows 0..7 valid (positions); rows 8..15 are aliased duplicates - skip.
    if (h < 2) {
      #pragma unroll
      for (int n = 0; n < 4; n++)
        #pragma unroll
        for (int v = 0; v < 4; v++)
          Ts[(rvb + v) * TSS + wid * 64 + n * 16 + co] = acc2[n][v];
    }
  }
  // NO barrier: Ts slice [*, wid*64..+64] is written and read by wave wid only.

  // ---- epilogue: residual from As (LDS), direct wide stores ----
  #pragma unroll
  for (int n = 0; n < 4; n++) {
    const int o = wid * 64 + n * 16 + co;
    const float C1 = c12[o];          // L2-hot; loaded here to keep term1 regs lean
    const float C2 = c12[KH + o];
    const int swzo = o >> 3;
    const int ob2 = (o & 7) * 2;
    #pragma unroll
    for (int m = 0; m < 3; m++) {
      int j0  = m * 16 + rvb;
      int pl0 = j0 / 6;
      int d0  = j0 - pl0 * 6;
      float mean0 = st[2 * pl0], rstd0 = st[2 * pl0 + 1];
      float t20   = Ts[pl0 * TSS + o];
      float cc0   = C1 - mean0 * rstd0 * C2;
      if (d0 < 3) {
        f32x4 ov;
        #pragma unroll
        for (int v = 0; v < 4; v++) {
          int j = j0 + v;
          unsigned short rx = *(const unsigned short*)(
              As + j * 1024 + ((swzo ^ (j & 7)) << 4) + ob2);
          ov[v] = bf2f(rx) + fmaxf(rstd0 * (acc1[m][n][v] + t20) + cc0, 0.f);
        }
        *(f32x4*)(out + (r0 + pl0) * DF + o * 6 + d0) = ov;
      } else {                               // d0 == 4: split 2 + 2
        int pl1 = pl0 + 1;
        float mean1 = st[2 * pl1], rstd1 = st[2 * pl1 + 1];
        float t21   = Ts[pl1 * TSS + o];
        float cc1   = C1 - mean1 * rstd1 * C2;
        f32x2 o0, o1;
        #pragma unroll
        for (int v = 0; v < 2; v++) {
          int j = j0 + v;
          unsigned short rx = *(const unsigned short*)(
              As + j * 1024 + ((swzo ^ (j & 7)) << 4) + ob2);
          o0[v] = bf2f(rx) + fmaxf(rstd0 * (acc1[m][n][v] + t20) + cc0, 0.f);
        }
        #pragma unroll
        for (int v = 2; v < 4; v++) {
          int j = j0 + v;
          unsigned short rx = *(const unsigned short*)(
              As + j * 1024 + ((swzo ^ (j & 7)) << 4) + ob2);
          o1[v - 2] = bf2f(rx) + fmaxf(rstd1 * (acc1[m][n][v] + t21) + cc1, 0.f);
        }
        *(f32x2*)(out + (r0 + pl0) * DF + o * 6 + 4) = o0;
        *(f32x2*)(out + (r0 + pl1) * DF + o * 6)     = o1;
      }
    }
  }
}

extern "C" void kernel_launch(void* const* d_in, const int* in_sizes, int n_in,
                              void* d_out, int out_size, void* d_ws, size_t ws_size,
                              hipStream_t stream) {
  (void)n_in; (void)out_size; (void)ws_size;
  const float* x  = (const float*)d_in[0];
  const float* cw = (const float*)d_in[1];
  const float* cb = (const float*)d_in[2];
  const float* nw = (const float*)d_in[3];
  const float* nb = (const float*)d_in[4];
  float* out = (float*)d_out;

  unsigned char* wbt = (unsigned char*)d_ws;                    // 1 MB images
  float* c12 = (float*)((char*)d_ws + (size_t)1024 * 1024);     // 4 KB

  prep_w<<<512, 256, 0, stream>>>(cw, cb, nw, nb, wbt, c12);

  const int R = in_sizes[0] / DF;            // 24576 positions
  fused_main<<<R / PPB, 512, 0, stream>>>(x, wbt, c12, out);
}

// Round 12
// 234.111 us; speedup vs baseline: 1.2367x; 1.0181x over previous
//
#include <hip/hip_runtime.h>
#include <stdint.h>
#include <stddef.h>

#define KH   512
#define DF   3072
#define EPSF 1e-5f
#define PPB  8            // positions per block
#define ROWS 48           // PPB*6
#define TSS  516          // Ts row stride (floats), padded

typedef __attribute__((ext_vector_type(4))) float f32x4;
typedef __attribute__((ext_vector_type(2))) float f32x2;
typedef __attribute__((ext_vector_type(8))) short bf16x8;

__device__ __forceinline__ unsigned short f2bf(float f) {
  union { float f; unsigned u; } c; c.f = f;
  unsigned u = c.u;
  u += 0x7fffu + ((u >> 16) & 1u);     // RNE
  return (unsigned short)(u >> 16);
}
__device__ __forceinline__ unsigned short f2bf_trunc(float f) {
  union { float f; unsigned u; } c; c.f = f;
  return (unsigned short)(c.u >> 16);  // truncation: 1 op
}
__device__ __forceinline__ float bf2f(unsigned short u) {
  union { unsigned u; float f; } c; c.u = ((unsigned)u) << 16;
  return c.f;
}

// Weight images (verified R5 layout): region A (0): alpha*gamma,
// region B (+512KB): beta_w*gamma.
// byte(f,s) = (((f>>2)*16 + s)*4 + (f&3))*1024 + (h*16+co)*16 + e*2,  f = o>>4.
// Per-wave per-step fragment read = contiguous 4KB = 4 coalesced 1KB dwordx4.
__global__ __launch_bounds__(256) void prep_w(const float* __restrict__ cw,
                                              const float* __restrict__ cb,
                                              const float* __restrict__ nw,
                                              const float* __restrict__ nb,
                                              unsigned char* __restrict__ wbt,
                                              float* __restrict__ c12) {
  const int o = blockIdx.x;
  const int t = threadIdx.x;
  const int wn = o >> 6, nn = (o >> 4) & 3, co = o & 15;
  float c1 = 0.f, c2 = 0.f;
  for (int k = t; k < KH; k += 256) {
    float w0 = cw[o * 1024 + 2 * k];
    float w1 = cw[o * 1024 + 2 * k + 1];
    float a  = w0 - w1;
    float g  = nw[k], b = nb[k];
    int s = k >> 5, kin = k & 31, h = kin >> 3, e = kin & 7;
    size_t base = (size_t)(((wn * 16 + s) * 4 + nn)) * 1024 + (h * 16 + co) * 16 + e * 2;
    *(unsigned short*)(wbt + base)          = f2bf(a * g);    // alpha*gamma
    *(unsigned short*)(wbt + base + 524288) = f2bf(w1 * g);   // beta_w*gamma
    float tt = a + 6.f * w1;
    c1 += tt * b;
    c2 += tt * g;
  }
  #pragma unroll
  for (int off = 32; off >= 1; off >>= 1) {
    c1 += __shfl_xor(c1, off);
    c2 += __shfl_xor(c2, off);
  }
  __shared__ float s1[4], s2[4];
  int wid = t >> 6, lane = t & 63;
  if (lane == 0) { s1[wid] = c1; s2[wid] = c2; }
  __syncthreads();
  if (t == 0) {
    c12[o]      = s1[0] + s1[1] + s1[2] + s1[3] + cb[o];
    c12[KH + o] = s2[0] + s2[1] + s2[2] + s2[3];
  }
}

// Block: 8 positions (48 rows) x 512 o. 512 threads = 8 waves; wave wid owns
// position wid (prologue) and o-slice wid*64..+64 (GEMM+epilogue).
// ONE barrier total. 3072 blocks, ~72.6 KB LDS -> 2 blocks/CU co-resident.
// Fused prologue: wave loads its position's contiguous 12 KB row; lane = k-group
// (8 consecutive k x 6 colors in registers) -> As rows via 6 ds_write_b128,
// LN stats via register reduce + shuffles, Sx from same registers.
__global__ __launch_bounds__(512, 4) void fused_main(
    const float* __restrict__ x,
    const unsigned char* __restrict__ wbt,
    const float* __restrict__ c12,
    float* __restrict__ out)
{
  __shared__ unsigned char As[ROWS * 1024];   // 48 KB raw-x panel (bf16, swizzled)
  __shared__ unsigned char Sx[PPB * 1024];    // 8 KB raw color-sum panel
  __shared__ float Ts[PPB * TSS];             // 16.1 KB term2 (f32)
  __shared__ float st[PPB * 2];

  const int tid  = threadIdx.x;
  const int lane = tid & 63;
  const int wid  = tid >> 6;     // 0..7 : o-slice AND position owner
  const int co   = lane & 15;
  const int h    = lane >> 4;
  const int rvb  = h << 2;
  const size_t r0 = (size_t)blockIdx.x * PPB;

  const unsigned char* wA = wbt + (size_t)wid * 65536;
  bf16x8 bvA[4], bvB[4];

  // ---- fused prologue: wave wid owns position r0+wid ----
  {
    const float* xr = x + (size_t)(r0 + wid) * DF + lane * 48;
    f32x4 q[12];
    #pragma unroll
    for (int i = 0; i < 12; i++) q[i] = *(const f32x4*)(xr + i * 4);

    // prefetch term1's step-0 B fragments (independent; hides L2 latency
    // across the barrier)
    #pragma unroll
    for (int n = 0; n < 4; n++)
      bvA[n] = *(const bf16x8*)(wA + n * 1024 + lane * 16);

    float vv[48];
    #pragma unroll
    for (int i = 0; i < 12; i++) {
      vv[4 * i] = q[i].x; vv[4 * i + 1] = q[i].y;
      vv[4 * i + 2] = q[i].z; vv[4 * i + 3] = q[i].w;
    }
    // LN stats
    float s = 0.f, sq = 0.f;
    #pragma unroll
    for (int i = 0; i < 48; i++) { s += vv[i]; sq += vv[i] * vv[i]; }
    #pragma unroll
    for (int off = 32; off >= 1; off >>= 1) {
      s  += __shfl_xor(s,  off);
      sq += __shfl_xor(sq, off);
    }
    float mean = s * (1.f / 3072.f);
    float var  = sq * (1.f / 3072.f) - mean * mean;
    float rstd = rsqrtf(var + EPSF);
    if (lane == 0) { st[2 * wid] = mean; st[2 * wid + 1] = rstd; }

    // As rows: lane holds k = lane*8..+8 for all 6 colors -> one b128 per row
    #pragma unroll
    for (int d = 0; d < 6; d++) {
      int row = wid * 6 + d;
      bf16x8 v;
      #pragma unroll
      for (int g = 0; g < 8; g++) v[g] = (short)f2bf_trunc(vv[g * 6 + d]);
      *(bf16x8*)(As + row * 1024 + ((lane ^ (row & 7)) << 4)) = v;
    }
    // Sx: raw color sums for the same 8 k
    bf16x8 sv;
    #pragma unroll
    for (int g = 0; g < 8; g++) {
      float ss = vv[g * 6] + vv[g * 6 + 1] + vv[g * 6 + 2] +
                 vv[g * 6 + 3] + vv[g * 6 + 4] + vv[g * 6 + 5];
      sv[g] = (short)f2bf_trunc(ss);
    }
    *(bf16x8*)(Sx + wid * 1024 + ((lane ^ (wid & 7)) << 4)) = sv;
  }
  __syncthreads();               // the ONLY barrier: As + Sx + st ready

  // ---- term1: 48x512 over K=512; A and B register double-buffered ----
  f32x4 acc1[3][4];
  #pragma unroll
  for (int m = 0; m < 3; m++)
    #pragma unroll
    for (int n = 0; n < 4; n++) acc1[m][n] = (f32x4){0.f, 0.f, 0.f, 0.f};

  int arow[3], ar7[3];
  #pragma unroll
  for (int m = 0; m < 3; m++) {
    int row = m * 16 + co;
    arow[m] = row * 1024;  ar7[m] = row & 7;
  }

  {
    bf16x8 afA[3], afB[3];
    #pragma unroll
    for (int m = 0; m < 3; m++)               // step-0 A fragments
      afA[m] = *(const bf16x8*)(As + arow[m] + ((h ^ ar7[m]) << 4));

    #pragma unroll 1
    for (int s = 0; s < 16; s += 2) {
      // prefetch step s+1 (A from LDS, B from L2)
      {
        int g6 = (s + 1) * 4 + h;
        #pragma unroll
        for (int m = 0; m < 3; m++)
          afB[m] = *(const bf16x8*)(As + arow[m] + ((g6 ^ ar7[m]) << 4));
        const unsigned char* pn = wA + (size_t)(s + 1) * 4096;
        #pragma unroll
        for (int n = 0; n < 4; n++)
          bvB[n] = *(const bf16x8*)(pn + n * 1024 + lane * 16);
      }
      // MFMA step s
      __builtin_amdgcn_s_setprio(1);
      #pragma unroll
      for (int m = 0; m < 3; m++)
        #pragma unroll
        for (int n = 0; n < 4; n++)
          acc1[m][n] = __builtin_amdgcn_mfma_f32_16x16x32_bf16(afA[m], bvA[n], acc1[m][n], 0, 0, 0);
      __builtin_amdgcn_s_setprio(0);
      // prefetch step s+2
      if (s + 2 < 16) {
        int g6 = (s + 2) * 4 + h;
        #pragma unroll
        for (int m = 0; m < 3; m++)
          afA[m] = *(const bf16x8*)(As + arow[m] + ((g6 ^ ar7[m]) << 4));
        const unsigned char* pn2 = wA + (size_t)(s + 2) * 4096;
        #pragma unroll
        for (int n = 0; n < 4; n++)
          bvA[n] = *(const bf16x8*)(pn2 + n * 1024 + lane * 16);
      }
      // MFMA step s+1
      __builtin_amdgcn_s_setprio(1);
      #pragma unroll
      for (int m = 0; m < 3; m++)
        #pragma unroll
        for (int n = 0; n < 4; n++)
          acc1[m][n] = __builtin_amdgcn_mfma_f32_16x16x32_bf16(afB[m], bvB[n], acc1[m][n], 0, 0, 0);
      __builtin_amdgcn_s_setprio(0);
    }
  }

  // ---- term2: 8x512 over K=512; same-wave o-slice; result -> Ts ----
  {
    f32x4 acc2[4];
    #pragma unroll
    for (int n = 0; n < 4; n++) acc2[n] = (f32x4){0.f, 0.f, 0.f, 0.f};
    const unsigned char* wB2 = wbt + 524288 + (size_t)wid * 65536;
    const int sxr = (co & 7);
    bf16x8 cA[4], cB[4];
    bf16x8 a2A, a2B;
    #pragma unroll
    for (int n = 0; n < 4; n++)
      cA[n] = *(const bf16x8*)(wB2 + n * 1024 + lane * 16);
    a2A = *(const bf16x8*)(Sx + sxr * 1024 + ((h ^ sxr) << 4));

    #pragma unroll 1
    for (int s = 0; s < 16; s += 2) {
      {
        int g6 = (s + 1) * 4 + h;
        a2B = *(const bf16x8*)(Sx + sxr * 1024 + ((g6 ^ sxr) << 4));
        const unsigned char* pn = wB2 + (size_t)(s + 1) * 4096;
        #pragma unroll
        for (int n = 0; n < 4; n++)
          cB[n] = *(const bf16x8*)(pn + n * 1024 + lane * 16);
      }
      __builtin_amdgcn_s_setprio(1);
      #pragma unroll
      for (int n = 0; n < 4; n++)
        acc2[n] = __builtin_amdgcn_mfma_f32_16x16x32_bf16(a2A, cA[n], acc2[n], 0, 0, 0);
      __builtin_amdgcn_s_setprio(0);
      if (s + 2 < 16) {
        int g6 = (s + 2) * 4 + h;
        a2A = *(const bf16x8*)(Sx + sxr * 1024 + ((g6 ^ sxr) << 4));
        const unsigned char* pn2 = wB2 + (size_t)(s + 2) * 4096;
        #pragma unroll
        for (int n = 0; n < 4; n++)
          cA[n] = *(const bf16x8*)(pn2 + n * 1024 + lane * 16);
      }
      __builtin_amdgcn_s_setprio(1);
      #pragma unroll
      for (int n = 0; n < 4; n++)
        acc2[n] = __builtin_amdgcn_mfma_f32_16x16x32_bf16(a2B, cB[n], acc2[n], 0, 0, 0);
      __builtin_amdgcn_s_setprio(0);
    }
    // rows 0..7 valid (positions); rows 8..15 are aliased duplicates - skip.
    if (h < 2) {
      #pragma unroll
      for (int n = 0; n < 4; n++)
        #pragma unroll
        for (int v = 0; v < 4; v++)
          Ts[(rvb + v) * TSS + wid * 64 + n * 16 + co] = acc2[n][v];
    }
  }
  // NO barrier: Ts slice [*, wid*64..+64] is written and read by wave wid only.

  // ---- epilogue: residual from As (LDS), direct wide stores ----
  #pragma unroll
  for (int n = 0; n < 4; n++) {
    const int o = wid * 64 + n * 16 + co;
    const float C1 = c12[o];          // L2-hot; loaded here to keep GEMM regs lean
    const float C2 = c12[KH + o];
    const int swzo = o >> 3;
    const int ob2 = (o & 7) * 2;
    #pragma unroll
    for (int m = 0; m < 3; m++) {
      int j0  = m * 16 + rvb;
      int pl0 = j0 / 6;
      int d0  = j0 - pl0 * 6;
      float mean0 = st[2 * pl0], rstd0 = st[2 * pl0 + 1];
      float t20   = Ts[pl0 * TSS + o];
      float cc0   = C1 - mean0 * rstd0 * C2;
      if (d0 < 3) {
        f32x4 ov;
        #pragma unroll
        for (int v = 0; v < 4; v++) {
          int j = j0 + v;
          unsigned short rx = *(const unsigned short*)(
              As + j * 1024 + ((swzo ^ (j & 7)) << 4) + ob2);
          ov[v] = bf2f(rx) + fmaxf(rstd0 * (acc1[m][n][v] + t20) + cc0, 0.f);
        }
        *(f32x4*)(out + (r0 + pl0) * DF + o * 6 + d0) = ov;
      } else {                               // d0 == 4: split 2 + 2
        int pl1 = pl0 + 1;
        float mean1 = st[2 * pl1], rstd1 = st[2 * pl1 + 1];
        float t21   = Ts[pl1 * TSS + o];
        float cc1   = C1 - mean1 * rstd1 * C2;
        f32x2 o0, o1;
        #pragma unroll
        for (int v = 0; v < 2; v++) {
          int j = j0 + v;
          unsigned short rx = *(const unsigned short*)(
              As + j * 1024 + ((swzo ^ (j & 7)) << 4) + ob2);
          o0[v] = bf2f(rx) + fmaxf(rstd0 * (acc1[m][n][v] + t20) + cc0, 0.f);
        }
        #pragma unroll
        for (int v = 2; v < 4; v++) {
          int j = j0 + v;
          unsigned short rx = *(const unsigned short*)(
              As + j * 1024 + ((swzo ^ (j & 7)) << 4) + ob2);
          o1[v - 2] = bf2f(rx) + fmaxf(rstd1 * (acc1[m][n][v] + t21) + cc1, 0.f);
        }
        *(f32x2*)(out + (r0 + pl0) * DF + o * 6 + 4) = o0;
        *(f32x2*)(out + (r0 + pl1) * DF + o * 6)     = o1;
      }
    }
  }
}

extern "C" void kernel_launch(void* const* d_in, const int* in_sizes, int n_in,
                              void* d_out, int out_size, void* d_ws, size_t ws_size,
                              hipStream_t stream) {
  (void)n_in; (void)out_size; (void)ws_size;
  const float* x  = (const float*)d_in[0];
  const float* cw = (const float*)d_in[1];
  const float* cb = (const float*)d_in[2];
  const float* nw = (const float*)d_in[3];
  const float* nb = (const float*)d_in[4];
  float* out = (float*)d_out;

  unsigned char* wbt = (unsigned char*)d_ws;                    // 1 MB images
  float* c12 = (float*)((char*)d_ws + (size_t)1024 * 1024);     // 4 KB

  prep_w<<<512, 256, 0, stream>>>(cw, cb, nw, nb, wbt, c12);

  const int R = in_sizes[0] / DF;            // 24576 positions
  fused_main<<<R / PPB, 512, 0, stream>>>(x, wbt, c12, out);
}